// Round 13
// baseline (647.018 us; speedup 1.0000x reference)
//
#include <hip/hip_runtime.h>
#include <math.h>

#define N_NODES_C  25000
#define N_EDGES_C  100000
#define N_GRAPHS_C 1000
#define EPB 128  // edges per block in msg_kernel

typedef __attribute__((ext_vector_type(8))) _Float16 f16x8;
typedef __attribute__((ext_vector_type(2))) _Float16 f16x2;
typedef __attribute__((ext_vector_type(4))) float   f32x4;

__device__ __forceinline__ float lrelu(float x) { return x > 0.f ? x : 0.01f * x; }
__device__ __forceinline__ float sigm(float x)  { return 1.f / (1.f + __expf(-x)); }
__device__ __forceinline__ f32x4 MFH(f16x8 a, f16x8 b, f32x4 c) {
  return __builtin_amdgcn_mfma_f32_16x16x32_f16(a, b, c, 0, 0, 0);
}

// ---------------------------------------------------------------- lin0 (LDS-staged weights)
__global__ __launch_bounds__(256) void lin0_kernel(const float* __restrict__ x,
                            const float* __restrict__ w, const float* __restrict__ b,
                            float* __restrict__ nodeF) {
  __shared__ float ws[64 * 15];
  __shared__ float bs[64];
  __shared__ float xr[4][16];
  const int tid = threadIdx.x;
  for (int i = tid; i < 896; i += 256) { int o = i / 14, j = i % 14; ws[o * 15 + j] = w[i]; }
  if (tid < 64) bs[tid] = b[tid];
  const int nl = tid >> 6, o = tid & 63;
  const int n = blockIdx.x * 4 + nl;
  if (o < 14 && n < N_NODES_C) xr[nl][o] = x[n * 14 + o];
  __syncthreads();
  if (n < N_NODES_C) {
    float s = bs[o];
#pragma unroll
    for (int j = 0; j < 14; ++j) s += xr[nl][j] * ws[o * 15 + j];
    nodeF[n * 64 + o] = lrelu(s);
  }
}

// ---------------------------------------------------------------- degree
__global__ void deg_kernel(const int* __restrict__ ei, float* __restrict__ deg) {
  int e = blockIdx.x * blockDim.x + threadIdx.x;
  if (e < N_EDGES_C) atomicAdd(&deg[ei[N_EDGES_C + e]], 1.f);
}

__global__ void invdeg_kernel(float* __restrict__ deg) {
  int n = blockIdx.x * blockDim.x + threadIdx.x;
  if (n < N_NODES_C) { float v = deg[n]; deg[n] = v > 0.f ? 1.f / v : 0.f; }
}

// graph offsets via binary search over sorted batch
__global__ void goff_kernel(const int* __restrict__ batch, int* __restrict__ goff) {
  int g = blockIdx.x * blockDim.x + threadIdx.x;
  if (g > N_GRAPHS_C) return;
  int lo = 0, hi = N_NODES_C;
  while (lo < hi) { int mid = (lo + hi) >> 1; if (batch[mid] < g) lo = mid + 1; else hi = mid; }
  goff[g] = lo;
}

// ---------------------------------------------------------------- GRU weight prep (fp16 frag-major)
// frag(t,kc) element (lane,j): o=t*16+(lane&15), d=kc*32+(lane>>4)*8+j
__global__ void prep_gru_kernel(const float* __restrict__ conv_root,
                                const float* __restrict__ w_ih, const float* __restrict__ w_hh,
                                _Float16* __restrict__ Rtp,
                                _Float16* __restrict__ Wip, _Float16* __restrict__ Whp) {
  int i = blockIdx.x * 256 + threadIdx.x;
  if (i < 12288) {
    int j = i & 7, lane = (i >> 3) & 63, kc = (i >> 9) & 1, t = i >> 10;
    int o = t * 16 + (lane & 15), d = kc * 32 + (lane >> 4) * 8 + j;
    if (i < 4096) Rtp[i] = (_Float16)conv_root[d * 64 + o];  // B[o,d] = root[d,o]
    Wip[i] = (_Float16)w_ih[o * 64 + d];
    Whp[i] = (_Float16)w_hh[o * 64 + d];
  }
}

// ---------------------------------------------------------------- W2 prep: frag-major fp16 image
// Wp[i]: i = (((d*4 + kc)*4 + ot)*64 + lane)*8 + j
//   o = ot*16+(lane&15), h = kc*32+(lane>>4)*8+j, value = W2[(d*64+o)*128+h]
//   -> for fixed (d,kc) the 4 ot-frags are contiguous (1024 B apart).
// B2p[i]: i = ((ot*2+kc2)*64+lane)*8+j ; o as above, d = kc2*32+(lane>>4)*8+j
__global__ __launch_bounds__(256) void prep_w2_kernel(
    const float* __restrict__ net_w2, const float* __restrict__ net_b2,
    _Float16* __restrict__ Wp, _Float16* __restrict__ B2p) {
  int i = blockIdx.x * 256 + threadIdx.x;  // < 524288
  {
    int j = i & 7, lane = (i >> 3) & 63, ot = (i >> 9) & 3, kc = (i >> 11) & 3, d = i >> 13;
    int col = lane & 15, kg = lane >> 4;
    int o = ot * 16 + col, h = kc * 32 + kg * 8 + j;
    Wp[i] = (_Float16)net_w2[((size_t)d * 64 + o) * 128 + h];
  }
  if (i < 4096) {
    int j = i & 7, lane = (i >> 3) & 63, kc2 = (i >> 9) & 1, ot = (i >> 10) & 3;
    int col = lane & 15, kg = lane >> 4;
    int o = ot * 16 + col, d = kc2 * 32 + kg * 8 + j;
    B2p[i] = (_Float16)net_b2[d * 64 + o];
  }
}

// ---------------------------------------------------------------- NNConv message + scatter
// msg = U @ W'^T + x @ B2,  U[e,d*128+h] = x[e,d]*A[e,h]  (fp16 in / fp32 acc)
// Block = 4 waves; wave (eh,kh) = 64 edges (eh half) x ALL 64 o x K-half (kh: kc pair).
// Each U-build feeds 4 MFMA (vs 2 in R12) -> U-build VALU per MFMA halved (1.13).
// kh partials merged via padded LDS reduction (xsT aliased, dead after d-loop);
// kh=0 waves scatter. B pipeline: R12's counted vmcnt(4) + sched_barrier discipline.
__global__ __launch_bounds__(256, 3) void msg_kernel(
    const float* __restrict__ nodef,     // [N,64]
    const int*   __restrict__ ei,        // [2,E]
    const float* __restrict__ eattr,     // [E,4]
    const float* __restrict__ net_w1,    // [128,4]
    const float* __restrict__ net_b1,    // [128]
    const _Float16* __restrict__ Wp,     // frag-major W2 fp16 (1 MB)
    const _Float16* __restrict__ B2p,    // frag-major b2 fp16 (8 KB)
    float* __restrict__ aggr)            // [N,64]
{
  __shared__ float red[2][64 * 68];    // 34.8 KB; first 16 KB aliased as xsT during compute
  __shared__ float w1s[128 * 5];       // 2.5 KB (w0..w3, b1) per hidden unit
  _Float16* xsT = (_Float16*)&red[0][0];  // [EPB][64], d ^ ((e&7)<<3)

  const int tid = threadIdx.x;         // 0..255
  const int e0 = blockIdx.x * EPB;

  // ---- stage W1+b1
  if (tid < 128) {
    float4 wv4 = *(const float4*)(net_w1 + tid * 4);
    w1s[tid * 5 + 0] = wv4.x; w1s[tid * 5 + 1] = wv4.y;
    w1s[tid * 5 + 2] = wv4.z; w1s[tid * 5 + 3] = wv4.w;
    w1s[tid * 5 + 4] = net_b1[tid];
  }
  // ---- stage x: xsT[e][d] (fp16, swizzled), 2 threads/edge
  {
    const int e = tid >> 1, dh = (tid & 1) * 32;
    int ge = e0 + e;
    const int esw = (e & 7) << 3;
#pragma unroll
    for (int jb = 0; jb < 4; ++jb) {
      int d = dh + jb * 8;
      float4 v0, v1;
      if (ge < N_EDGES_C) {
        const float4* nf4 = (const float4*)(nodef + (size_t)ei[ge] * 64 + d);
        v0 = nf4[0]; v1 = nf4[1];
      } else {
        v0 = make_float4(0.f, 0.f, 0.f, 0.f); v1 = v0;
      }
      f16x8 pk;
      pk[0] = (_Float16)v0.x; pk[1] = (_Float16)v0.y; pk[2] = (_Float16)v0.z; pk[3] = (_Float16)v0.w;
      pk[4] = (_Float16)v1.x; pk[5] = (_Float16)v1.y; pk[6] = (_Float16)v1.z; pk[7] = (_Float16)v1.w;
      *(f16x8*)&xsT[e * 64 + (d ^ esw)] = pk;
    }
  }

  const int lane = tid & 63, wv = tid >> 6;
  const int eh = wv & 1;               // edge half
  const int kh = wv >> 1;              // K half (kc pair kh*2, kh*2+1)
  const int e0w = eh * 64;
  const int col = lane & 15;
  const int kg  = lane >> 4;
  const int swz = (col & 7) << 3;

  __syncthreads();  // staging done

  // ---- acc init: x @ B2 for kc2 = kh (summed across kh in the reduction)
  f32x4 acc[4][4];
#pragma unroll
  for (int eb = 0; eb < 4; ++eb)
#pragma unroll
    for (int ot = 0; ot < 4; ++ot) acc[eb][ot] = 0.f;
  {
    f16x8 xf[4];
#pragma unroll
    for (int eb = 0; eb < 4; ++eb)
      xf[eb] = *(const f16x8*)&xsT[(e0w + eb * 16 + col) * 64 + ((kh * 32 + kg * 8) ^ swz)];
#pragma unroll
    for (int ot = 0; ot < 4; ++ot) {
      f16x8 b2f = *(const f16x8*)(B2p + ((ot * 2 + kh) * 64 + lane) * 8);
#pragma unroll
      for (int eb = 0; eb < 4; ++eb) acc[eb][ot] = MFH(xf[eb], b2f, acc[eb][ot]);
    }
  }

  // ---- A-frags: Af[eb][kk] for kc = kh*2+kk, h = kc*32 + kg*8 + j
  f16x8 Af[4][2];
  {
    float4 at[4];
#pragma unroll
    for (int eb = 0; eb < 4; ++eb) {
      int ge = e0 + e0w + eb * 16 + col;
      at[eb] = (ge < N_EDGES_C) ? *(const float4*)(eattr + (size_t)ge * 4)
                                : make_float4(0.f, 0.f, 0.f, 0.f);
    }
#pragma unroll
    for (int kk = 0; kk < 2; ++kk) {
      float4 wr[8]; float wb[8];
#pragma unroll
      for (int j = 0; j < 8; ++j) {
        int hq = (kh * 2 + kk) * 32 + kg * 8 + j;
        wr[j] = *(const float4*)&w1s[hq * 5];
        wb[j] = w1s[hq * 5 + 4];
      }
#pragma unroll
      for (int eb = 0; eb < 4; ++eb) {
        f16x8 F;
#pragma unroll
        for (int j = 0; j < 8; ++j) {
          float a = wb[j] + at[eb].x * wr[j].x + at[eb].y * wr[j].y
                          + at[eb].z * wr[j].z + at[eb].w * wr[j].w;
          F[j] = (_Float16)lrelu(a);
        }
        Af[eb][kk] = F;
      }
    }
  }

#define ISSUE(BUF, ADDR)                                                  \
  asm volatile("global_load_dwordx4 %0, %4, off\n\t"                      \
               "global_load_dwordx4 %1, %4, off offset:1024\n\t"          \
               "global_load_dwordx4 %2, %4, off offset:2048\n\t"          \
               "global_load_dwordx4 %3, %4, off offset:3072"              \
               : "=&v"(BUF[0]), "=&v"(BUF[1]), "=&v"(BUF[2]), "=&v"(BUF[3]) \
               : "v"(ADDR)                                                \
               : "memory")
#define COMPUTE(BUF, KK)                                                  \
  {                                                                       \
    _Pragma("unroll")                                                     \
    for (int eb = 0; eb < 4; ++eb) {                                      \
      union { f16x8 v; f16x2 pp[4]; } af, Uu;                             \
      af.v = Af[eb][KK];                                                  \
      _Pragma("unroll")                                                   \
      for (int q = 0; q < 4; ++q) Uu.pp[q] = af.pp[q] * x2[eb];           \
      acc[eb][0] = MFH(Uu.v, BUF[0], acc[eb][0]);                         \
      acc[eb][1] = MFH(Uu.v, BUF[1], acc[eb][1]);                         \
      acc[eb][2] = MFH(Uu.v, BUF[2], acc[eb][2]);                         \
      acc[eb][3] = MFH(Uu.v, BUF[3], acc[eb][3]);                         \
    }                                                                     \
  }

  // ---- pipelined d-loop: sub-step = (d, kk); 4 frags (ot) per sub-step.
  // Wp frag base for (d, kc): Wp + (d*4 + kc)*2048 + lane*8  (halfs)
  const _Float16* pcur = Wp + (size_t)(kh * 2) * 2048 + lane * 8;
  f16x8 B0[4], B1[4];
  ISSUE(B0, pcur);          // (d=0, kk=0)
  ISSUE(B1, pcur + 2048);   // (d=0, kk=1)
  const _Float16* pnx = pcur + 8192;  // (d=1, kk=0)

#pragma unroll 1
  for (int d8 = 0; d8 < 64; d8 += 8) {
    union XU { f16x8 v; unsigned u[4]; };
    XU XV[4];
#pragma unroll
    for (int eb = 0; eb < 4; ++eb)
      XV[eb].v = *(const f16x8*)&xsT[(e0w + eb * 16 + col) * 64 + (d8 ^ swz)];
#pragma unroll
    for (int dj = 0; dj < 8; ++dj) {
      const int d = d8 + dj;
      f16x2 x2[4];
#pragma unroll
      for (int eb = 0; eb < 4; ++eb) {
        unsigned dw = XV[eb].u[dj >> 1];
        unsigned xd = __builtin_amdgcn_perm(dw, dw, (dj & 1) ? 0x03020302u : 0x01000100u);
        union { unsigned u; f16x2 h; } c; c.u = xd; x2[eb] = c.h;
      }
      // kk = 0
      asm volatile("s_waitcnt vmcnt(4)");
      __builtin_amdgcn_sched_barrier(0);
      COMPUTE(B0, 0);
      __builtin_amdgcn_sched_barrier(0);
      if (d < 63) ISSUE(B0, pnx);
      // kk = 1
      if (d < 63) { asm volatile("s_waitcnt vmcnt(4)"); }
      else        { asm volatile("s_waitcnt vmcnt(0)"); }
      __builtin_amdgcn_sched_barrier(0);
      COMPUTE(B1, 1);
      __builtin_amdgcn_sched_barrier(0);
      if (d < 63) ISSUE(B1, pnx + 2048);
      pnx += 8192;
    }
  }
#undef ISSUE
#undef COMPUTE

  // ---- merge kh partials via LDS (xsT dead now), then kh=0 waves scatter
  __syncthreads();
  if (kh == 1) {
#pragma unroll
    for (int eb = 0; eb < 4; ++eb)
#pragma unroll
      for (int ot = 0; ot < 4; ++ot)
#pragma unroll
        for (int r = 0; r < 4; ++r)
          red[eh][(eb * 16 + kg * 4 + r) * 68 + ot * 16 + col] = acc[eb][ot][r];
  }
  __syncthreads();
  if (kh == 0) {
#pragma unroll
    for (int eb = 0; eb < 4; ++eb) {
#pragma unroll
      for (int r = 0; r < 4; ++r) {
        int e = e0w + eb * 16 + kg * 4 + r;
        int ge = e0 + e;
        if (ge < N_EDGES_C) {
          int dn = ei[N_EDGES_C + ge];
#pragma unroll
          for (int ot = 0; ot < 4; ++ot) {
            float v = acc[eb][ot][r] + red[eh][(eb * 16 + kg * 4 + r) * 68 + ot * 16 + col];
            atomicAdd(&aggr[(size_t)dn * 64 + ot * 16 + col], v);
          }
        }
      }
    }
  }
}

// ---------------------------------------------------------------- root matmul + GRU (fp16 MFMA)
// Block: 64 nodes, 4 waves x 16 nodes. Zeroes aggr in place after reading.
__global__ __launch_bounds__(256) void node_update_kernel(
    float* __restrict__ aggr, const float* __restrict__ invdeg,
    const _Float16* __restrict__ Rtp, const _Float16* __restrict__ Wip,
    const _Float16* __restrict__ Whp,
    const float* __restrict__ conv_bias,
    const float* __restrict__ b_ih, const float* __restrict__ b_hh,
    float* __restrict__ nodeF)
{
  __shared__ _Float16 ms[4][16 * 64];  // per-wave m tile, swizzled (8 KB)

  const int tid = threadIdx.x, lane = tid & 63, wv = tid >> 6;
  const int col = lane & 15, kg = lane >> 4;
  const int nwb = blockIdx.x * 64 + wv * 16;

  int arow = nwb + col; if (arow >= N_NODES_C) arow = N_NODES_C - 1;
  f16x8 nf[2];
#pragma unroll
  for (int kc = 0; kc < 2; ++kc) {
    f32x4 v0 = *(const f32x4*)(nodeF + (size_t)arow * 64 + kc * 32 + kg * 8);
    f32x4 v1 = *(const f32x4*)(nodeF + (size_t)arow * 64 + kc * 32 + kg * 8 + 4);
    f16x8 F;
#pragma unroll
    for (int j = 0; j < 4; ++j) { F[j] = (_Float16)v0[j]; F[4 + j] = (_Float16)v1[j]; }
    nf[kc] = F;
  }

  // ---- Phase 1: root = h @ Rt^T + conv_bias (8 MFMA)
  f32x4 racc[4];
#pragma unroll
  for (int t = 0; t < 4; ++t) racc[t] = conv_bias[t * 16 + col];
#pragma unroll
  for (int t = 0; t < 4; ++t)
#pragma unroll
    for (int kc = 0; kc < 2; ++kc)
      racc[t] = MFH(nf[kc], *(const f16x8*)(Rtp + t * 1024 + kc * 512 + lane * 8), racc[t]);

  // ---- Epilogue 1: m = lrelu(aggr*invdeg + racc); aggr <- 0; m -> LDS (fp16, swizzled)
  float invd[4]; int nrow[4];
#pragma unroll
  for (int r = 0; r < 4; ++r) {
    int nn = nwb + kg * 4 + r; nrow[r] = nn;
    invd[r] = (nn < N_NODES_C) ? invdeg[nn] : 0.f;
  }
#pragma unroll
  for (int t = 0; t < 4; ++t) {
#pragma unroll
    for (int r = 0; r < 4; ++r) {
      int nn = nrow[r];
      float ag = 0.f;
      if (nn < N_NODES_C) {
        size_t idx = (size_t)nn * 64 + t * 16 + col;
        ag = aggr[idx];
        aggr[idx] = 0.f;  // re-zero for next msg step / next replay
      }
      float mval = lrelu(ag * invd[r] + racc[t][r]);
      int nl = kg * 4 + r;
      int dsw = (t * 16 + col) ^ ((nl & 7) << 3);
      ms[wv][nl * 64 + dsw] = (_Float16)mval;
    }
  }
  __syncthreads();

  f16x8 ma[2];
#pragma unroll
  for (int kc = 0; kc < 2; ++kc)
    ma[kc] = *(const f16x8*)&ms[wv][col * 64 + ((kc * 32 + kg * 8) ^ ((col & 7) << 3))];

  // ---- Phase 2: gi = m @ Wi^T + b_ih ; gh = h @ Wh^T + b_hh  (48 MFMA)
  f32x4 gi[12], gh[12];
#pragma unroll
  for (int t = 0; t < 12; ++t) { gi[t] = b_ih[t * 16 + col]; gh[t] = b_hh[t * 16 + col]; }
#pragma unroll
  for (int t = 0; t < 12; ++t)
#pragma unroll
    for (int kc = 0; kc < 2; ++kc) {
      gi[t] = MFH(ma[kc], *(const f16x8*)(Wip + t * 1024 + kc * 512 + lane * 8), gi[t]);
      gh[t] = MFH(nf[kc], *(const f16x8*)(Whp + t * 1024 + kc * 512 + lane * 8), gh[t]);
    }

  // ---- Epilogue 2: GRU combine, h -> nodeF
#pragma unroll
  for (int t = 0; t < 4; ++t) {
#pragma unroll
    for (int r = 0; r < 4; ++r) {
      int nn = nrow[r];
      if (nn >= N_NODES_C) continue;
      size_t idx = (size_t)nn * 64 + t * 16 + col;
      float hv = nodeF[idx];
      float rr = sigm(gi[t][r] + gh[t][r]);
      float zz = sigm(gi[t + 4][r] + gh[t + 4][r]);
      float nv = tanhf(gi[t + 8][r] + rr * gh[t + 8][r]);
      nodeF[idx] = (1.f - zz) * nv + zz * hv;
    }
  }
}

// ---------------------------------------------------------------- fused Set2Set (3 steps) + final linear
__global__ __launch_bounds__(64) void set2set_kernel(
    const float* __restrict__ nodeF, const int* __restrict__ goff,
    const float* __restrict__ w_ih, const float* __restrict__ w_hh,
    const float* __restrict__ b_ih, const float* __restrict__ b_hh,
    const float* __restrict__ lw, const float* __restrict__ lb,
    float* __restrict__ ebuf, float* __restrict__ dout)
{
  const int g = blockIdx.x, t = threadIdx.x;
  __shared__ float qs[128], hs[64];
  float hl = 0.f, cl = 0.f;
  qs[t] = 0.f; qs[64 + t] = 0.f;
  const int s0 = goff[g], s1 = goff[g + 1];

  for (int step = 0; step < 3; ++step) {
    hs[t] = hl;
    __syncthreads();
    float gv[4];
#pragma unroll
    for (int k = 0; k < 4; ++k) {
      float s = b_ih[k * 64 + t] + b_hh[k * 64 + t];
      const float4* wi4 = (const float4*)(w_ih + (k * 64 + t) * 128);
#pragma unroll 8
      for (int j = 0; j < 32; ++j) {
        float4 w = wi4[j];
        s += qs[4 * j] * w.x + qs[4 * j + 1] * w.y + qs[4 * j + 2] * w.z + qs[4 * j + 3] * w.w;
      }
      const float4* wh4 = (const float4*)(w_hh + (k * 64 + t) * 64);
#pragma unroll 8
      for (int j = 0; j < 16; ++j) {
        float4 w = wh4[j];
        s += hs[4 * j] * w.x + hs[4 * j + 1] * w.y + hs[4 * j + 2] * w.z + hs[4 * j + 3] * w.w;
      }
      gv[k] = s;
    }
    cl = sigm(gv[1]) * cl + sigm(gv[0]) * tanhf(gv[2]);
    hl = sigm(gv[3]) * tanhf(cl);
    const float qv = hl;

    // segment softmax attention
    float emax = -3.0e38f;
    for (int n = s0; n < s1; ++n) {
      float p = nodeF[n * 64 + t] * qv;
#pragma unroll
      for (int off = 32; off > 0; off >>= 1) p += __shfl_down(p, off);
      float en = __shfl(p, 0);
      if (t == 0) ebuf[n] = en;
      emax = fmaxf(emax, en);
    }
    __syncthreads();  // drain ebuf writes
    float lsum = 0.f;
    for (int n = s0 + t; n < s1; n += 64) {
      float ex = __expf(ebuf[n] - emax);
      ebuf[n] = ex;
      lsum += ex;
    }
#pragma unroll
    for (int off = 32; off > 0; off >>= 1) lsum += __shfl_down(lsum, off);
    float denom = __shfl(lsum, 0);
    __syncthreads();  // drain exp writes
    float r = 0.f;
    for (int n = s0; n < s1; ++n) r += ebuf[n] * nodeF[n * 64 + t];
    if (s1 > s0) r /= denom;
    qs[t] = qv; qs[64 + t] = r;  // visible after next loop-top barrier
  }
  __syncthreads();
  float s = qs[t] * lw[t] + qs[64 + t] * lw[64 + t];
#pragma unroll
  for (int off = 32; off > 0; off >>= 1) s += __shfl_down(s, off);
  if (t == 0) dout[g] = s + lb[0];
}

// ---------------------------------------------------------------- launch
extern "C" void kernel_launch(void* const* d_in, const int* in_sizes, int n_in,
                              void* d_out, int out_size, void* d_ws, size_t ws_size,
                              hipStream_t stream) {
  const float* x         = (const float*)d_in[0];
  const int*   ei        = (const int*)  d_in[1];
  const float* eattr     = (const float*)d_in[2];
  const int*   batch     = (const int*)  d_in[3];
  const float* lin0_w    = (const float*)d_in[4];
  const float* lin0_b    = (const float*)d_in[5];
  const float* net_w1    = (const float*)d_in[6];
  const float* net_b1    = (const float*)d_in[7];
  const float* net_w2    = (const float*)d_in[8];
  const float* net_b2    = (const float*)d_in[9];
  const float* conv_root = (const float*)d_in[10];
  const float* conv_bias = (const float*)d_in[11];
  const float* gru_w_ih  = (const float*)d_in[12];
  const float* gru_w_hh  = (const float*)d_in[13];
  const float* gru_b_ih  = (const float*)d_in[14];
  const float* gru_b_hh  = (const float*)d_in[15];
  const float* lstm_w_ih = (const float*)d_in[16];
  const float* lstm_w_hh = (const float*)d_in[17];
  const float* lstm_b_ih = (const float*)d_in[18];
  const float* lstm_b_hh = (const float*)d_in[19];
  const float* lin_w     = (const float*)d_in[20];
  const float* lin_b     = (const float*)d_in[21];

  // workspace layout (~13.1 MB)
  float* ws    = (float*)d_ws;
  float* nodeF = ws;                         // 1,600,000 f
  float* aggr  = nodeF + 1600000;            // 1,600,000 f
  float* deg   = aggr + 1600000;             //    25,000 f
  float* ebuf  = deg + 25000;                //    25,000 f
  int*   goff  = (int*)(ebuf + 25000);       //     1,024 i
  _Float16* Rtp = (_Float16*)(goff + 1024);  //     4,096 h
  _Float16* Wip = Rtp + 4096;                //    12,288 h
  _Float16* Whp = Wip + 12288;               //    12,288 h
  _Float16* Wp  = Whp + 12288;               //   524,288 h
  _Float16* B2p = Wp + 524288;               //     4,096 h

  hipMemsetAsync(deg, 0, 25000 * sizeof(float), stream);
  hipMemsetAsync(aggr, 0, 1600000 * sizeof(float), stream);  // node_update re-zeroes thereafter

  lin0_kernel<<<(N_NODES_C + 3) / 4, 256, 0, stream>>>(x, lin0_w, lin0_b, nodeF);
  deg_kernel<<<(N_EDGES_C + 255) / 256, 256, 0, stream>>>(ei, deg);
  invdeg_kernel<<<(N_NODES_C + 255) / 256, 256, 0, stream>>>(deg);
  goff_kernel<<<(N_GRAPHS_C + 256) / 256, 256, 0, stream>>>(batch, goff);
  prep_gru_kernel<<<48, 256, 0, stream>>>(conv_root, gru_w_ih, gru_w_hh, Rtp, Wip, Whp);
  prep_w2_kernel<<<2048, 256, 0, stream>>>(net_w2, net_b2, Wp, B2p);

  for (int step = 0; step < 3; ++step) {
    msg_kernel<<<(N_EDGES_C + EPB - 1) / EPB, 256, 0, stream>>>(
        nodeF, ei, eattr, net_w1, net_b1, Wp, B2p, aggr);
    node_update_kernel<<<(N_NODES_C + 63) / 64, 256, 0, stream>>>(
        aggr, deg, Rtp, Wip, Whp, conv_bias, gru_b_ih, gru_b_hh, nodeF);
  }

  set2set_kernel<<<N_GRAPHS_C, 64, 0, stream>>>(
      nodeF, goff, lstm_w_ih, lstm_w_hh, lstm_b_ih, lstm_b_hh, lin_w, lin_b, ebuf, (float*)d_out);
}

// Round 14
// 587.866 us; speedup vs baseline: 1.1006x; 1.1006x over previous
//
#include <hip/hip_runtime.h>
#include <math.h>

#define N_NODES_C  25000
#define N_EDGES_C  100000
#define N_GRAPHS_C 1000
#define EPB 128  // edges per block in msg_kernel

typedef __attribute__((ext_vector_type(8))) _Float16 f16x8;
typedef __attribute__((ext_vector_type(2))) _Float16 f16x2;
typedef __attribute__((ext_vector_type(4))) float   f32x4;

__device__ __forceinline__ float lrelu(float x) { return x > 0.f ? x : 0.01f * x; }
__device__ __forceinline__ float sigm(float x)  { return 1.f / (1.f + __expf(-x)); }
__device__ __forceinline__ f32x4 MFH(f16x8 a, f16x8 b, f32x4 c) {
  return __builtin_amdgcn_mfma_f32_16x16x32_f16(a, b, c, 0, 0, 0);
}

// ---------------------------------------------------------------- lin0 (LDS-staged weights)
__global__ __launch_bounds__(256) void lin0_kernel(const float* __restrict__ x,
                            const float* __restrict__ w, const float* __restrict__ b,
                            float* __restrict__ nodeF) {
  __shared__ float ws[64 * 15];
  __shared__ float bs[64];
  __shared__ float xr[4][16];
  const int tid = threadIdx.x;
  for (int i = tid; i < 896; i += 256) { int o = i / 14, j = i % 14; ws[o * 15 + j] = w[i]; }
  if (tid < 64) bs[tid] = b[tid];
  const int nl = tid >> 6, o = tid & 63;
  const int n = blockIdx.x * 4 + nl;
  if (o < 14 && n < N_NODES_C) xr[nl][o] = x[n * 14 + o];
  __syncthreads();
  if (n < N_NODES_C) {
    float s = bs[o];
#pragma unroll
    for (int j = 0; j < 14; ++j) s += xr[nl][j] * ws[o * 15 + j];
    nodeF[n * 64 + o] = lrelu(s);
  }
}

// ---------------------------------------------------------------- degree
__global__ void deg_kernel(const int* __restrict__ ei, float* __restrict__ deg) {
  int e = blockIdx.x * blockDim.x + threadIdx.x;
  if (e < N_EDGES_C) atomicAdd(&deg[ei[N_EDGES_C + e]], 1.f);
}

__global__ void invdeg_kernel(float* __restrict__ deg) {
  int n = blockIdx.x * blockDim.x + threadIdx.x;
  if (n < N_NODES_C) { float v = deg[n]; deg[n] = v > 0.f ? 1.f / v : 0.f; }
}

// graph offsets via binary search over sorted batch
__global__ void goff_kernel(const int* __restrict__ batch, int* __restrict__ goff) {
  int g = blockIdx.x * blockDim.x + threadIdx.x;
  if (g > N_GRAPHS_C) return;
  int lo = 0, hi = N_NODES_C;
  while (lo < hi) { int mid = (lo + hi) >> 1; if (batch[mid] < g) lo = mid + 1; else hi = mid; }
  goff[g] = lo;
}

// ---------------------------------------------------------------- GRU weight prep (fp16 frag-major)
// frag(t,kc) element (lane,j): o=t*16+(lane&15), d=kc*32+(lane>>4)*8+j
__global__ void prep_gru_kernel(const float* __restrict__ conv_root,
                                const float* __restrict__ w_ih, const float* __restrict__ w_hh,
                                _Float16* __restrict__ Rtp,
                                _Float16* __restrict__ Wip, _Float16* __restrict__ Whp) {
  int i = blockIdx.x * 256 + threadIdx.x;
  if (i < 12288) {
    int j = i & 7, lane = (i >> 3) & 63, kc = (i >> 9) & 1, t = i >> 10;
    int o = t * 16 + (lane & 15), d = kc * 32 + (lane >> 4) * 8 + j;
    if (i < 4096) Rtp[i] = (_Float16)conv_root[d * 64 + o];  // B[o,d] = root[d,o]
    Wip[i] = (_Float16)w_ih[o * 64 + d];
    Whp[i] = (_Float16)w_hh[o * 64 + d];
  }
}

// ---------------------------------------------------------------- W2 prep: frag-major fp16 image
// Wp[i]: i = ((((d*2+oh)*2+p)*4 + q)*64 + lane)*8 + j ; q = kci*2+ob
//   o = oh*32+ob*16+(lane&15), h = (p*2+kci)*32+(lane>>4)*8+j, value = W2[(d*64+o)*128+h]
// B2p[i]: i = (((oh*2+ob)*2+kc2)*64+lane)*8+j ; o as above, d = kc2*32+(lane>>4)*8+j
__global__ __launch_bounds__(256) void prep_w2_kernel(
    const float* __restrict__ net_w2, const float* __restrict__ net_b2,
    _Float16* __restrict__ Wp, _Float16* __restrict__ B2p) {
  int i = blockIdx.x * 256 + threadIdx.x;  // < 524288
  {
    int j = i & 7, lane = (i >> 3) & 63, q = (i >> 9) & 3, p = (i >> 11) & 1;
    int oh = (i >> 12) & 1, d = i >> 13;
    int kci = q >> 1, ob = q & 1;
    int col = lane & 15, kg = lane >> 4;
    int o = oh * 32 + ob * 16 + col, h = (p * 2 + kci) * 32 + kg * 8 + j;
    Wp[i] = (_Float16)net_w2[((size_t)d * 64 + o) * 128 + h];
  }
  if (i < 4096) {
    int j = i & 7, lane = (i >> 3) & 63, kc2 = (i >> 9) & 1, ob = (i >> 10) & 1, oh = (i >> 11) & 1;
    int col = lane & 15, kg = lane >> 4;
    int o = oh * 32 + ob * 16 + col, d = kc2 * 32 + kg * 8 + j;
    B2p[i] = (_Float16)net_b2[d * 64 + o];
  }
}

// ---------------------------------------------------------------- NNConv message + scatter
// msg = U @ W'^T + x @ B2,  U[e,d*128+h] = x[e,d]*A[e,h]  (fp16 in / fp32 acc)
// Block = 4 waves x 256 threads; wave tile = 64 edges x 32 outputs (R12 topology).
// d-loop pipeline DEPTH 2: prologue issues d0,d1; per step: wait vmcnt(4) ->
// COMPUTE(d) -> ISSUE(d+2). Each load gets ~2 compute windows (~600 cyc) of slack
// before its wait, covering L2 latency spikes, with the same 2 buffers (no VGPR cost).
__global__ __launch_bounds__(256, 3) void msg_kernel(
    const float* __restrict__ nodef,     // [N,64]
    const int*   __restrict__ ei,        // [2,E]
    const float* __restrict__ eattr,     // [E,4]
    const float* __restrict__ net_w1,    // [128,4]
    const float* __restrict__ net_b1,    // [128]
    const _Float16* __restrict__ Wp,     // frag-major W2 fp16 (1 MB)
    const _Float16* __restrict__ B2p,    // frag-major b2 fp16 (8 KB)
    float* __restrict__ aggr)            // [N,64]
{
  __shared__ _Float16 xsT[EPB * 64];   // 16 KB  xsT[e][d ^ ((e&7)<<3)]
  __shared__ float    w1s[128 * 5];    // 2.5 KB (w0..w3, b1) per hidden unit

  const int tid = threadIdx.x;         // 0..255
  const int e0 = blockIdx.x * EPB;

  // ---- stage W1+b1
  if (tid < 128) {
    float4 wv = *(const float4*)(net_w1 + tid * 4);
    w1s[tid * 5 + 0] = wv.x; w1s[tid * 5 + 1] = wv.y;
    w1s[tid * 5 + 2] = wv.z; w1s[tid * 5 + 3] = wv.w;
    w1s[tid * 5 + 4] = net_b1[tid];
  }
  // ---- stage x: xsT[e][d] (fp16, swizzled), 2 threads/edge
  {
    const int e = tid >> 1, dh = (tid & 1) * 32;
    int ge = e0 + e;
    const int esw = (e & 7) << 3;
#pragma unroll
    for (int jb = 0; jb < 4; ++jb) {
      int d = dh + jb * 8;
      float4 v0, v1;
      if (ge < N_EDGES_C) {
        const float4* nf4 = (const float4*)(nodef + (size_t)ei[ge] * 64 + d);
        v0 = nf4[0]; v1 = nf4[1];
      } else {
        v0 = make_float4(0.f, 0.f, 0.f, 0.f); v1 = v0;
      }
      f16x8 pk;
      pk[0] = (_Float16)v0.x; pk[1] = (_Float16)v0.y; pk[2] = (_Float16)v0.z; pk[3] = (_Float16)v0.w;
      pk[4] = (_Float16)v1.x; pk[5] = (_Float16)v1.y; pk[6] = (_Float16)v1.z; pk[7] = (_Float16)v1.w;
      *(f16x8*)&xsT[e * 64 + (d ^ esw)] = pk;
    }
  }

  const int lane = tid & 63, wv = tid >> 6;
  const int e0w = (wv & 1) * 64;       // wave edge half
  const int oh  = wv >> 1;             // wave output half (32 cols)
  const int col = lane & 15;
  const int kg  = lane >> 4;
  const int swz = (col & 7) << 3;

  __syncthreads();  // staging done; rest of kernel is LDS read-only

  // ---- acc init: x @ B2 (16 MFMA)
  f32x4 acc[4][2];
#pragma unroll
  for (int eb = 0; eb < 4; ++eb) { acc[eb][0] = 0.f; acc[eb][1] = 0.f; }
#pragma unroll
  for (int ob = 0; ob < 2; ++ob)
#pragma unroll
    for (int kc2 = 0; kc2 < 2; ++kc2) {
      f16x8 b2f = *(const f16x8*)(B2p + oh * 2048 + ob * 1024 + kc2 * 512 + lane * 8);
#pragma unroll
      for (int eb = 0; eb < 4; ++eb) {
        f16x8 xf = *(const f16x8*)&xsT[(e0w + eb * 16 + col) * 64 + ((kc2 * 32 + kg * 8) ^ swz)];
        acc[eb][ob] = MFH(xf, b2f, acc[eb][ob]);
      }
    }

  // asm: issue one d's 4 B-frags from one address (frag stride 1024 B, imm offsets).
  // EARLY-CLOBBER outputs: dests must not alias the address pair.
#define ISSUE(BUF, ADDR)                                                  \
  asm volatile("global_load_dwordx4 %0, %4, off\n\t"                      \
               "global_load_dwordx4 %1, %4, off offset:1024\n\t"          \
               "global_load_dwordx4 %2, %4, off offset:2048\n\t"          \
               "global_load_dwordx4 %3, %4, off offset:3072"              \
               : "=&v"(BUF[0]), "=&v"(BUF[1]), "=&v"(BUF[2]), "=&v"(BUF[3]) \
               : "v"(ADDR)                                                \
               : "memory")
#define COMPUTE(BUF, XV, J)                                               \
  {                                                                       \
    _Pragma("unroll")                                                     \
    for (int eb = 0; eb < 4; ++eb) {                                      \
      unsigned dw = XV[eb].u[(J) >> 1];                                   \
      unsigned xd = __builtin_amdgcn_perm(dw, dw, ((J) & 1) ? 0x03020302u : 0x01000100u); \
      f16x2 x2; { union { unsigned u; f16x2 h; } c; c.u = xd; x2 = c.h; } \
      _Pragma("unroll")                                                   \
      for (int kci = 0; kci < 2; ++kci) {                                 \
        union { f16x8 v; f16x2 pp[4]; } af, Uu;                           \
        af.v = Af[eb][kci];                                               \
        _Pragma("unroll")                                                 \
        for (int q = 0; q < 4; ++q) Uu.pp[q] = af.pp[q] * x2;             \
        acc[eb][0] = MFH(Uu.v, BUF[kci * 2 + 0], acc[eb][0]);             \
        acc[eb][1] = MFH(Uu.v, BUF[kci * 2 + 1], acc[eb][1]);             \
      }                                                                   \
    }                                                                     \
  }

  // ---- 2 passes over kc-halves; per pass: 8 A-frags in regs, then pipelined d-loop
  const _Float16* wp_base = Wp + oh * 4096 + lane * 8;  // + p*2048 + d*8192 (halfs)
#pragma unroll 1
  for (int p = 0; p < 2; ++p) {
    // A-frags: A[e][h] = lrelu(eattr[e] . w1[h] + b1[h]), h = (p*2+kci)*32 + kg*8 + j
    f16x8 Af[4][2];
    {
      float4 at[4];
#pragma unroll
      for (int eb = 0; eb < 4; ++eb) {
        int ge = e0 + e0w + eb * 16 + col;
        at[eb] = (ge < N_EDGES_C) ? *(const float4*)(eattr + (size_t)ge * 4)
                                  : make_float4(0.f, 0.f, 0.f, 0.f);
      }
#pragma unroll
      for (int kci = 0; kci < 2; ++kci) {
        float4 wr[8]; float wb[8];
#pragma unroll
        for (int j = 0; j < 8; ++j) {
          int hq = (p * 2 + kci) * 32 + kg * 8 + j;
          wr[j] = *(const float4*)&w1s[hq * 5];
          wb[j] = w1s[hq * 5 + 4];
        }
#pragma unroll
        for (int eb = 0; eb < 4; ++eb) {
          f16x8 F;
#pragma unroll
          for (int j = 0; j < 8; ++j) {
            float a = wb[j] + at[eb].x * wr[j].x + at[eb].y * wr[j].y
                            + at[eb].z * wr[j].z + at[eb].w * wr[j].w;
            F[j] = (_Float16)lrelu(a);
          }
          Af[eb][kci] = F;
        }
      }
    }

    const _Float16* wp_p = wp_base + p * 2048;
    f16x8 B0[4], B1[4];
    ISSUE(B0, wp_p);                     // d=0 in flight
    ISSUE(B1, wp_p + 8192);              // d=1 in flight (depth 2)

#pragma unroll 1
    for (int d8 = 0; d8 < 64; d8 += 8) {
      union XU { f16x8 v; unsigned u[4]; };
      XU XV[4];
#pragma unroll
      for (int eb = 0; eb < 4; ++eb)
        XV[eb].v = *(const f16x8*)&xsT[(e0w + eb * 16 + col) * 64 + (d8 ^ swz)];
#pragma unroll
      for (int j = 0; j < 8; ++j) {
        const int d = d8 + j;
        if (d < 63) { asm volatile("s_waitcnt vmcnt(4)"); }  // d's 4 done; d+1 in flight
        else        { asm volatile("s_waitcnt vmcnt(0)"); }  // last d: drain
        __builtin_amdgcn_sched_barrier(0);                    // rule #18
        if ((j & 1) == 0) { COMPUTE(B0, XV, j); } else { COMPUTE(B1, XV, j); }
        __builtin_amdgcn_sched_barrier(0);
        if (d < 62) {
          const _Float16* adr = wp_p + (size_t)(d + 2) * 8192;
          if ((j & 1) == 0) { ISSUE(B0, adr); } else { ISSUE(B1, adr); }
        }
      }
    }
  }
#undef ISSUE
#undef COMPUTE

  // ---- scatter-add into aggr[dst]
  const int o0w = oh * 32;
#pragma unroll
  for (int eb = 0; eb < 4; ++eb) {
#pragma unroll
    for (int r = 0; r < 4; ++r) {
      int e = e0w + eb * 16 + kg * 4 + r;
      int ge = e0 + e;
      if (ge < N_EDGES_C) {
        int dn = ei[N_EDGES_C + ge];
        atomicAdd(&aggr[(size_t)dn * 64 + o0w + col],      acc[eb][0][r]);
        atomicAdd(&aggr[(size_t)dn * 64 + o0w + 16 + col], acc[eb][1][r]);
      }
    }
  }
}

// ---------------------------------------------------------------- root matmul + GRU (fp16 MFMA)
// Block: 64 nodes, 4 waves x 16 nodes. Zeroes aggr in place after reading.
__global__ __launch_bounds__(256) void node_update_kernel(
    float* __restrict__ aggr, const float* __restrict__ invdeg,
    const _Float16* __restrict__ Rtp, const _Float16* __restrict__ Wip,
    const _Float16* __restrict__ Whp,
    const float* __restrict__ conv_bias,
    const float* __restrict__ b_ih, const float* __restrict__ b_hh,
    float* __restrict__ nodeF)
{
  __shared__ _Float16 ms[4][16 * 64];  // per-wave m tile, swizzled (8 KB)

  const int tid = threadIdx.x, lane = tid & 63, wv = tid >> 6;
  const int col = lane & 15, kg = lane >> 4;
  const int nwb = blockIdx.x * 64 + wv * 16;

  int arow = nwb + col; if (arow >= N_NODES_C) arow = N_NODES_C - 1;
  f16x8 nf[2];
#pragma unroll
  for (int kc = 0; kc < 2; ++kc) {
    f32x4 v0 = *(const f32x4*)(nodeF + (size_t)arow * 64 + kc * 32 + kg * 8);
    f32x4 v1 = *(const f32x4*)(nodeF + (size_t)arow * 64 + kc * 32 + kg * 8 + 4);
    f16x8 F;
#pragma unroll
    for (int j = 0; j < 4; ++j) { F[j] = (_Float16)v0[j]; F[4 + j] = (_Float16)v1[j]; }
    nf[kc] = F;
  }

  // ---- Phase 1: root = h @ Rt^T + conv_bias (8 MFMA)
  f32x4 racc[4];
#pragma unroll
  for (int t = 0; t < 4; ++t) racc[t] = conv_bias[t * 16 + col];
#pragma unroll
  for (int t = 0; t < 4; ++t)
#pragma unroll
    for (int kc = 0; kc < 2; ++kc)
      racc[t] = MFH(nf[kc], *(const f16x8*)(Rtp + t * 1024 + kc * 512 + lane * 8), racc[t]);

  // ---- Epilogue 1: m = lrelu(aggr*invdeg + racc); aggr <- 0; m -> LDS (fp16, swizzled)
  float invd[4]; int nrow[4];
#pragma unroll
  for (int r = 0; r < 4; ++r) {
    int nn = nwb + kg * 4 + r; nrow[r] = nn;
    invd[r] = (nn < N_NODES_C) ? invdeg[nn] : 0.f;
  }
#pragma unroll
  for (int t = 0; t < 4; ++t) {
#pragma unroll
    for (int r = 0; r < 4; ++r) {
      int nn = nrow[r];
      float ag = 0.f;
      if (nn < N_NODES_C) {
        size_t idx = (size_t)nn * 64 + t * 16 + col;
        ag = aggr[idx];
        aggr[idx] = 0.f;  // re-zero for next msg step / next replay
      }
      float mval = lrelu(ag * invd[r] + racc[t][r]);
      int nl = kg * 4 + r;
      int dsw = (t * 16 + col) ^ ((nl & 7) << 3);
      ms[wv][nl * 64 + dsw] = (_Float16)mval;
    }
  }
  __syncthreads();

  f16x8 ma[2];
#pragma unroll
  for (int kc = 0; kc < 2; ++kc)
    ma[kc] = *(const f16x8*)&ms[wv][col * 64 + ((kc * 32 + kg * 8) ^ ((col & 7) << 3))];

  // ---- Phase 2: gi = m @ Wi^T + b_ih ; gh = h @ Wh^T + b_hh  (48 MFMA)
  f32x4 gi[12], gh[12];
#pragma unroll
  for (int t = 0; t < 12; ++t) { gi[t] = b_ih[t * 16 + col]; gh[t] = b_hh[t * 16 + col]; }
#pragma unroll
  for (int t = 0; t < 12; ++t)
#pragma unroll
    for (int kc = 0; kc < 2; ++kc) {
      gi[t] = MFH(ma[kc], *(const f16x8*)(Wip + t * 1024 + kc * 512 + lane * 8), gi[t]);
      gh[t] = MFH(nf[kc], *(const f16x8*)(Whp + t * 1024 + kc * 512 + lane * 8), gh[t]);
    }

  // ---- Epilogue 2: GRU combine, h -> nodeF
#pragma unroll
  for (int t = 0; t < 4; ++t) {
#pragma unroll
    for (int r = 0; r < 4; ++r) {
      int nn = nrow[r];
      if (nn >= N_NODES_C) continue;
      size_t idx = (size_t)nn * 64 + t * 16 + col;
      float hv = nodeF[idx];
      float rr = sigm(gi[t][r] + gh[t][r]);
      float zz = sigm(gi[t + 4][r] + gh[t + 4][r]);
      float nv = tanhf(gi[t + 8][r] + rr * gh[t + 8][r]);
      nodeF[idx] = (1.f - zz) * nv + zz * hv;
    }
  }
}

// ---------------------------------------------------------------- fused Set2Set (3 steps) + final linear
__global__ __launch_bounds__(64) void set2set_kernel(
    const float* __restrict__ nodeF, const int* __restrict__ goff,
    const float* __restrict__ w_ih, const float* __restrict__ w_hh,
    const float* __restrict__ b_ih, const float* __restrict__ b_hh,
    const float* __restrict__ lw, const float* __restrict__ lb,
    float* __restrict__ ebuf, float* __restrict__ dout)
{
  const int g = blockIdx.x, t = threadIdx.x;
  __shared__ float qs[128], hs[64];
  float hl = 0.f, cl = 0.f;
  qs[t] = 0.f; qs[64 + t] = 0.f;
  const int s0 = goff[g], s1 = goff[g + 1];

  for (int step = 0; step < 3; ++step) {
    hs[t] = hl;
    __syncthreads();
    float gv[4];
#pragma unroll
    for (int k = 0; k < 4; ++k) {
      float s = b_ih[k * 64 + t] + b_hh[k * 64 + t];
      const float4* wi4 = (const float4*)(w_ih + (k * 64 + t) * 128);
#pragma unroll 8
      for (int j = 0; j < 32; ++j) {
        float4 w = wi4[j];
        s += qs[4 * j] * w.x + qs[4 * j + 1] * w.y + qs[4 * j + 2] * w.z + qs[4 * j + 3] * w.w;
      }
      const float4* wh4 = (const float4*)(w_hh + (k * 64 + t) * 64);
#pragma unroll 8
      for (int j = 0; j < 16; ++j) {
        float4 w = wh4[j];
        s += hs[4 * j] * w.x + hs[4 * j + 1] * w.y + hs[4 * j + 2] * w.z + hs[4 * j + 3] * w.w;
      }
      gv[k] = s;
    }
    cl = sigm(gv[1]) * cl + sigm(gv[0]) * tanhf(gv[2]);
    hl = sigm(gv[3]) * tanhf(cl);
    const float qv = hl;

    // segment softmax attention
    float emax = -3.0e38f;
    for (int n = s0; n < s1; ++n) {
      float p = nodeF[n * 64 + t] * qv;
#pragma unroll
      for (int off = 32; off > 0; off >>= 1) p += __shfl_down(p, off);
      float en = __shfl(p, 0);
      if (t == 0) ebuf[n] = en;
      emax = fmaxf(emax, en);
    }
    __syncthreads();  // drain ebuf writes
    float lsum = 0.f;
    for (int n = s0 + t; n < s1; n += 64) {
      float ex = __expf(ebuf[n] - emax);
      ebuf[n] = ex;
      lsum += ex;
    }
#pragma unroll
    for (int off = 32; off > 0; off >>= 1) lsum += __shfl_down(lsum, off);
    float denom = __shfl(lsum, 0);
    __syncthreads();  // drain exp writes
    float r = 0.f;
    for (int n = s0; n < s1; ++n) r += ebuf[n] * nodeF[n * 64 + t];
    if (s1 > s0) r /= denom;
    qs[t] = qv; qs[64 + t] = r;  // visible after next loop-top barrier
  }
  __syncthreads();
  float s = qs[t] * lw[t] + qs[64 + t] * lw[64 + t];
#pragma unroll
  for (int off = 32; off > 0; off >>= 1) s += __shfl_down(s, off);
  if (t == 0) dout[g] = s + lb[0];
}

// ---------------------------------------------------------------- launch
extern "C" void kernel_launch(void* const* d_in, const int* in_sizes, int n_in,
                              void* d_out, int out_size, void* d_ws, size_t ws_size,
                              hipStream_t stream) {
  const float* x         = (const float*)d_in[0];
  const int*   ei        = (const int*)  d_in[1];
  const float* eattr     = (const float*)d_in[2];
  const int*   batch     = (const int*)  d_in[3];
  const float* lin0_w    = (const float*)d_in[4];
  const float* lin0_b    = (const float*)d_in[5];
  const float* net_w1    = (const float*)d_in[6];
  const float* net_b1    = (const float*)d_in[7];
  const float* net_w2    = (const float*)d_in[8];
  const float* net_b2    = (const float*)d_in[9];
  const float* conv_root = (const float*)d_in[10];
  const float* conv_bias = (const float*)d_in[11];
  const float* gru_w_ih  = (const float*)d_in[12];
  const float* gru_w_hh  = (const float*)d_in[13];
  const float* gru_b_ih  = (const float*)d_in[14];
  const float* gru_b_hh  = (const float*)d_in[15];
  const float* lstm_w_ih = (const float*)d_in[16];
  const float* lstm_w_hh = (const float*)d_in[17];
  const float* lstm_b_ih = (const float*)d_in[18];
  const float* lstm_b_hh = (const float*)d_in[19];
  const float* lin_w     = (const float*)d_in[20];
  const float* lin_b     = (const float*)d_in[21];

  // workspace layout (~13.1 MB)
  float* ws    = (float*)d_ws;
  float* nodeF = ws;                         // 1,600,000 f
  float* aggr  = nodeF + 1600000;            // 1,600,000 f
  float* deg   = aggr + 1600000;             //    25,000 f
  float* ebuf  = deg + 25000;                //    25,000 f
  int*   goff  = (int*)(ebuf + 25000);       //     1,024 i
  _Float16* Rtp = (_Float16*)(goff + 1024);  //     4,096 h
  _Float16* Wip = Rtp + 4096;                //    12,288 h
  _Float16* Whp = Wip + 12288;               //    12,288 h
  _Float16* Wp  = Whp + 12288;               //   524,288 h
  _Float16* B2p = Wp + 524288;               //     4,096 h

  hipMemsetAsync(deg, 0, 25000 * sizeof(float), stream);
  hipMemsetAsync(aggr, 0, 1600000 * sizeof(float), stream);  // node_update re-zeroes thereafter

  lin0_kernel<<<(N_NODES_C + 3) / 4, 256, 0, stream>>>(x, lin0_w, lin0_b, nodeF);
  deg_kernel<<<(N_EDGES_C + 255) / 256, 256, 0, stream>>>(ei, deg);
  invdeg_kernel<<<(N_NODES_C + 255) / 256, 256, 0, stream>>>(deg);
  goff_kernel<<<(N_GRAPHS_C + 256) / 256, 256, 0, stream>>>(batch, goff);
  prep_gru_kernel<<<48, 256, 0, stream>>>(conv_root, gru_w_ih, gru_w_hh, Rtp, Wip, Whp);
  prep_w2_kernel<<<2048, 256, 0, stream>>>(net_w2, net_b2, Wp, B2p);

  for (int step = 0; step < 3; ++step) {
    msg_kernel<<<(N_EDGES_C + EPB - 1) / EPB, 256, 0, stream>>>(
        nodeF, ei, eattr, net_w1, net_b1, Wp, B2p, aggr);
    node_update_kernel<<<(N_NODES_C + 63) / 64, 256, 0, stream>>>(
        aggr, deg, Rtp, Wip, Whp, conv_bias, gru_b_ih, gru_b_hh, nodeF);
  }

  set2set_kernel<<<N_GRAPHS_C, 64, 0, stream>>>(
      nodeF, goff, lstm_w_ih, lstm_w_hh, lstm_b_ih, lstm_b_hh, lin_w, lin_b, ebuf, (float*)d_out);
}

// Round 15
// 565.216 us; speedup vs baseline: 1.1447x; 1.0401x over previous
//
#include <hip/hip_runtime.h>
#include <math.h>

#define N_NODES_C  25000
#define N_EDGES_C  100000
#define N_GRAPHS_C 1000
#define EPB 128  // edges per block in msg_kernel

typedef __attribute__((ext_vector_type(8))) _Float16 f16x8;
typedef __attribute__((ext_vector_type(2))) _Float16 f16x2;
typedef __attribute__((ext_vector_type(4))) float   f32x4;

__device__ __forceinline__ float lrelu(float x) { return x > 0.f ? x : 0.01f * x; }
__device__ __forceinline__ float sigm(float x)  { return 1.f / (1.f + __expf(-x)); }
__device__ __forceinline__ f32x4 MFH(f16x8 a, f16x8 b, f32x4 c) {
  return __builtin_amdgcn_mfma_f32_16x16x32_f16(a, b, c, 0, 0, 0);
}

// ---------------------------------------------------------------- lin0 (LDS-staged weights)
__global__ __launch_bounds__(256) void lin0_kernel(const float* __restrict__ x,
                            const float* __restrict__ w, const float* __restrict__ b,
                            float* __restrict__ nodeF) {
  __shared__ float ws[64 * 15];
  __shared__ float bs[64];
  __shared__ float xr[4][16];
  const int tid = threadIdx.x;
  for (int i = tid; i < 896; i += 256) { int o = i / 14, j = i % 14; ws[o * 15 + j] = w[i]; }
  if (tid < 64) bs[tid] = b[tid];
  const int nl = tid >> 6, o = tid & 63;
  const int n = blockIdx.x * 4 + nl;
  if (o < 14 && n < N_NODES_C) xr[nl][o] = x[n * 14 + o];
  __syncthreads();
  if (n < N_NODES_C) {
    float s = bs[o];
#pragma unroll
    for (int j = 0; j < 14; ++j) s += xr[nl][j] * ws[o * 15 + j];
    nodeF[n * 64 + o] = lrelu(s);
  }
}

// ---------------------------------------------------------------- degree + graph offsets (merged)
__global__ void deg_kernel(const int* __restrict__ ei, const int* __restrict__ batch,
                           float* __restrict__ deg, int* __restrict__ goff) {
  int e = blockIdx.x * blockDim.x + threadIdx.x;
  if (e < N_EDGES_C) atomicAdd(&deg[ei[N_EDGES_C + e]], 1.f);
  if (e <= N_GRAPHS_C) {
    int lo = 0, hi = N_NODES_C;
    while (lo < hi) { int mid = (lo + hi) >> 1; if (batch[mid] < e) lo = mid + 1; else hi = mid; }
    goff[e] = lo;
  }
}

__global__ void invdeg_kernel(float* __restrict__ deg) {
  int n = blockIdx.x * blockDim.x + threadIdx.x;
  if (n < N_NODES_C) { float v = deg[n]; deg[n] = v > 0.f ? 1.f / v : 0.f; }
}

// ---------------------------------------------------------------- all weight prep (merged)
// GRU frag(t,kc) element (lane,j): o=t*16+(lane&15), d=kc*32+(lane>>4)*8+j
// Wp[i]: i = ((((d*2+oh)*2+p)*4 + q)*64 + lane)*8 + j ; q = kci*2+ob
//   o = oh*32+ob*16+(lane&15), h = (p*2+kci)*32+(lane>>4)*8+j, value = W2[(d*64+o)*128+h]
// B2p[i]: i = (((oh*2+ob)*2+kc2)*64+lane)*8+j ; o as above, d = kc2*32+(lane>>4)*8+j
__global__ __launch_bounds__(256) void prep_kernel(
    const float* __restrict__ net_w2, const float* __restrict__ net_b2,
    const float* __restrict__ conv_root,
    const float* __restrict__ w_ih, const float* __restrict__ w_hh,
    _Float16* __restrict__ Wp, _Float16* __restrict__ B2p,
    _Float16* __restrict__ Rtp, _Float16* __restrict__ Wip, _Float16* __restrict__ Whp) {
  int i = blockIdx.x * 256 + threadIdx.x;  // < 524288
  {
    int j = i & 7, lane = (i >> 3) & 63, q = (i >> 9) & 3, p = (i >> 11) & 1;
    int oh = (i >> 12) & 1, d = i >> 13;
    int kci = q >> 1, ob = q & 1;
    int col = lane & 15, kg = lane >> 4;
    int o = oh * 32 + ob * 16 + col, h = (p * 2 + kci) * 32 + kg * 8 + j;
    Wp[i] = (_Float16)net_w2[((size_t)d * 64 + o) * 128 + h];
  }
  if (i < 4096) {
    int j = i & 7, lane = (i >> 3) & 63, kc2 = (i >> 9) & 1, ob = (i >> 10) & 1, oh = (i >> 11) & 1;
    int col = lane & 15, kg = lane >> 4;
    int o = oh * 32 + ob * 16 + col, d = kc2 * 32 + kg * 8 + j;
    B2p[i] = (_Float16)net_b2[d * 64 + o];
  }
  if (i < 12288) {
    int j = i & 7, lane = (i >> 3) & 63, kc = (i >> 9) & 1, t = i >> 10;
    int o = t * 16 + (lane & 15), d = kc * 32 + (lane >> 4) * 8 + j;
    if (i < 4096) Rtp[i] = (_Float16)conv_root[d * 64 + o];  // B[o,d] = root[d,o]
    Wip[i] = (_Float16)w_ih[o * 64 + d];
    Whp[i] = (_Float16)w_hh[o * 64 + d];
  }
}

// ---------------------------------------------------------------- NNConv message + scatter
// msg = U @ W'^T + x @ B2,  U[e,d*128+h] = x[e,d]*A[e,h]  (fp16 in / fp32 acc)
// Block = 4 waves x 256 threads; wave tile = 64 edges x 32 outputs (R12 topology).
// d-loop pipeline depth 2: prologue issues d0,d1; per step: wait vmcnt(4) ->
// COMPUTE(d) -> ISSUE(d+2). Counted waits + sched_barrier (rule #18).
__global__ __launch_bounds__(256, 3) void msg_kernel(
    const float* __restrict__ nodef,     // [N,64]
    const int*   __restrict__ ei,        // [2,E]
    const float* __restrict__ eattr,     // [E,4]
    const float* __restrict__ net_w1,    // [128,4]
    const float* __restrict__ net_b1,    // [128]
    const _Float16* __restrict__ Wp,     // frag-major W2 fp16 (1 MB)
    const _Float16* __restrict__ B2p,    // frag-major b2 fp16 (8 KB)
    float* __restrict__ aggr)            // [N,64]
{
  __shared__ _Float16 xsT[EPB * 64];   // 16 KB  xsT[e][d ^ ((e&7)<<3)]
  __shared__ float    w1s[128 * 5];    // 2.5 KB (w0..w3, b1) per hidden unit

  const int tid = threadIdx.x;         // 0..255
  const int e0 = blockIdx.x * EPB;

  // ---- stage W1+b1
  if (tid < 128) {
    float4 wv = *(const float4*)(net_w1 + tid * 4);
    w1s[tid * 5 + 0] = wv.x; w1s[tid * 5 + 1] = wv.y;
    w1s[tid * 5 + 2] = wv.z; w1s[tid * 5 + 3] = wv.w;
    w1s[tid * 5 + 4] = net_b1[tid];
  }
  // ---- stage x: xsT[e][d] (fp16, swizzled), 2 threads/edge
  {
    const int e = tid >> 1, dh = (tid & 1) * 32;
    int ge = e0 + e;
    const int esw = (e & 7) << 3;
#pragma unroll
    for (int jb = 0; jb < 4; ++jb) {
      int d = dh + jb * 8;
      float4 v0, v1;
      if (ge < N_EDGES_C) {
        const float4* nf4 = (const float4*)(nodef + (size_t)ei[ge] * 64 + d);
        v0 = nf4[0]; v1 = nf4[1];
      } else {
        v0 = make_float4(0.f, 0.f, 0.f, 0.f); v1 = v0;
      }
      f16x8 pk;
      pk[0] = (_Float16)v0.x; pk[1] = (_Float16)v0.y; pk[2] = (_Float16)v0.z; pk[3] = (_Float16)v0.w;
      pk[4] = (_Float16)v1.x; pk[5] = (_Float16)v1.y; pk[6] = (_Float16)v1.z; pk[7] = (_Float16)v1.w;
      *(f16x8*)&xsT[e * 64 + (d ^ esw)] = pk;
    }
  }

  const int lane = tid & 63, wv = tid >> 6;
  const int e0w = (wv & 1) * 64;       // wave edge half
  const int oh  = wv >> 1;             // wave output half (32 cols)
  const int col = lane & 15;
  const int kg  = lane >> 4;
  const int swz = (col & 7) << 3;

  __syncthreads();  // staging done; rest of kernel is LDS read-only

  // ---- acc init: x @ B2 (16 MFMA)
  f32x4 acc[4][2];
#pragma unroll
  for (int eb = 0; eb < 4; ++eb) { acc[eb][0] = 0.f; acc[eb][1] = 0.f; }
#pragma unroll
  for (int ob = 0; ob < 2; ++ob)
#pragma unroll
    for (int kc2 = 0; kc2 < 2; ++kc2) {
      f16x8 b2f = *(const f16x8*)(B2p + oh * 2048 + ob * 1024 + kc2 * 512 + lane * 8);
#pragma unroll
      for (int eb = 0; eb < 4; ++eb) {
        f16x8 xf = *(const f16x8*)&xsT[(e0w + eb * 16 + col) * 64 + ((kc2 * 32 + kg * 8) ^ swz)];
        acc[eb][ob] = MFH(xf, b2f, acc[eb][ob]);
      }
    }

  // ---- eattr hoisted once (reused by both kc passes)
  float4 at[4];
#pragma unroll
  for (int eb = 0; eb < 4; ++eb) {
    int ge = e0 + e0w + eb * 16 + col;
    at[eb] = (ge < N_EDGES_C) ? *(const float4*)(eattr + (size_t)ge * 4)
                              : make_float4(0.f, 0.f, 0.f, 0.f);
  }

#define ISSUE(BUF, ADDR)                                                  \
  asm volatile("global_load_dwordx4 %0, %4, off\n\t"                      \
               "global_load_dwordx4 %1, %4, off offset:1024\n\t"          \
               "global_load_dwordx4 %2, %4, off offset:2048\n\t"          \
               "global_load_dwordx4 %3, %4, off offset:3072"              \
               : "=&v"(BUF[0]), "=&v"(BUF[1]), "=&v"(BUF[2]), "=&v"(BUF[3]) \
               : "v"(ADDR)                                                \
               : "memory")
#define COMPUTE(BUF, XV, J)                                               \
  {                                                                       \
    _Pragma("unroll")                                                     \
    for (int eb = 0; eb < 4; ++eb) {                                      \
      unsigned dw = XV[eb].u[(J) >> 1];                                   \
      unsigned xd = __builtin_amdgcn_perm(dw, dw, ((J) & 1) ? 0x03020302u : 0x01000100u); \
      f16x2 x2; { union { unsigned u; f16x2 h; } c; c.u = xd; x2 = c.h; } \
      _Pragma("unroll")                                                   \
      for (int kci = 0; kci < 2; ++kci) {                                 \
        union { f16x8 v; f16x2 pp[4]; } af, Uu;                           \
        af.v = Af[eb][kci];                                               \
        _Pragma("unroll")                                                 \
        for (int q = 0; q < 4; ++q) Uu.pp[q] = af.pp[q] * x2;             \
        acc[eb][0] = MFH(Uu.v, BUF[kci * 2 + 0], acc[eb][0]);             \
        acc[eb][1] = MFH(Uu.v, BUF[kci * 2 + 1], acc[eb][1]);             \
      }                                                                   \
    }                                                                     \
  }

  // ---- 2 passes over kc-halves; per pass: 8 A-frags in regs, then pipelined d-loop
  const _Float16* wp_base = Wp + oh * 4096 + lane * 8;  // + p*2048 + d*8192 (halfs)
#pragma unroll 1
  for (int p = 0; p < 2; ++p) {
    // A-frags: A[e][h] = lrelu(eattr[e] . w1[h] + b1[h]), h = (p*2+kci)*32 + kg*8 + j
    f16x8 Af[4][2];
#pragma unroll
    for (int kci = 0; kci < 2; ++kci) {
      float4 wr[8]; float wb[8];
#pragma unroll
      for (int j = 0; j < 8; ++j) {
        int hq = (p * 2 + kci) * 32 + kg * 8 + j;
        wr[j] = *(const float4*)&w1s[hq * 5];
        wb[j] = w1s[hq * 5 + 4];
      }
#pragma unroll
      for (int eb = 0; eb < 4; ++eb) {
        f16x8 F;
#pragma unroll
        for (int j = 0; j < 8; ++j) {
          float a = wb[j] + at[eb].x * wr[j].x + at[eb].y * wr[j].y
                          + at[eb].z * wr[j].z + at[eb].w * wr[j].w;
          F[j] = (_Float16)lrelu(a);
        }
        Af[eb][kci] = F;
      }
    }

    const _Float16* wp_p = wp_base + p * 2048;
    f16x8 B0[4], B1[4];
    ISSUE(B0, wp_p);                     // d=0 in flight
    ISSUE(B1, wp_p + 8192);              // d=1 in flight (depth 2)

#pragma unroll 1
    for (int d8 = 0; d8 < 64; d8 += 8) {
      union XU { f16x8 v; unsigned u[4]; };
      XU XV[4];
#pragma unroll
      for (int eb = 0; eb < 4; ++eb)
        XV[eb].v = *(const f16x8*)&xsT[(e0w + eb * 16 + col) * 64 + (d8 ^ swz)];
#pragma unroll
      for (int j = 0; j < 8; ++j) {
        const int d = d8 + j;
        if (d < 63) { asm volatile("s_waitcnt vmcnt(4)"); }  // d done; d+1 in flight
        else        { asm volatile("s_waitcnt vmcnt(0)"); }  // last d: drain
        __builtin_amdgcn_sched_barrier(0);                    // rule #18
        if ((j & 1) == 0) { COMPUTE(B0, XV, j); } else { COMPUTE(B1, XV, j); }
        __builtin_amdgcn_sched_barrier(0);
        if (d < 62) {
          const _Float16* adr = wp_p + (size_t)(d + 2) * 8192;
          if ((j & 1) == 0) { ISSUE(B0, adr); } else { ISSUE(B1, adr); }
        }
      }
    }
  }
#undef ISSUE
#undef COMPUTE

  // ---- scatter-add into aggr[dst]
  const int o0w = oh * 32;
#pragma unroll
  for (int eb = 0; eb < 4; ++eb) {
#pragma unroll
    for (int r = 0; r < 4; ++r) {
      int e = e0w + eb * 16 + kg * 4 + r;
      int ge = e0 + e;
      if (ge < N_EDGES_C) {
        int dn = ei[N_EDGES_C + ge];
        atomicAdd(&aggr[(size_t)dn * 64 + o0w + col],      acc[eb][0][r]);
        atomicAdd(&aggr[(size_t)dn * 64 + o0w + 16 + col], acc[eb][1][r]);
      }
    }
  }
}

// ---------------------------------------------------------------- root matmul + GRU (fp16 MFMA)
// Block: 32 nodes, 2 waves x 16 nodes (782 blocks for latency hiding).
// aggr reads hoisted BEFORE Phase-1 MFMA so root compute covers their latency.
__global__ __launch_bounds__(128) void node_update_kernel(
    float* __restrict__ aggr, const float* __restrict__ invdeg,
    const _Float16* __restrict__ Rtp, const _Float16* __restrict__ Wip,
    const _Float16* __restrict__ Whp,
    const float* __restrict__ conv_bias,
    const float* __restrict__ b_ih, const float* __restrict__ b_hh,
    float* __restrict__ nodeF)
{
  __shared__ _Float16 ms[2][16 * 64];  // per-wave m tile, swizzled (4 KB)

  const int tid = threadIdx.x, lane = tid & 63, wv = tid >> 6;
  const int col = lane & 15, kg = lane >> 4;
  const int nwb = blockIdx.x * 32 + wv * 16;

  // ---- hoisted loads: invdeg + aggr (latency overlapped by Phase-1 below)
  float invd[4]; int nrow[4];
#pragma unroll
  for (int r = 0; r < 4; ++r) {
    int nn = nwb + kg * 4 + r; nrow[r] = nn;
    invd[r] = (nn < N_NODES_C) ? invdeg[nn] : 0.f;
  }
  float ag[4][4];
#pragma unroll
  for (int t = 0; t < 4; ++t)
#pragma unroll
    for (int r = 0; r < 4; ++r) {
      int nn = nrow[r];
      ag[t][r] = (nn < N_NODES_C) ? aggr[(size_t)nn * 64 + t * 16 + col] : 0.f;
    }

  int arow = nwb + col; if (arow >= N_NODES_C) arow = N_NODES_C - 1;
  f16x8 nf[2];
#pragma unroll
  for (int kc = 0; kc < 2; ++kc) {
    f32x4 v0 = *(const f32x4*)(nodeF + (size_t)arow * 64 + kc * 32 + kg * 8);
    f32x4 v1 = *(const f32x4*)(nodeF + (size_t)arow * 64 + kc * 32 + kg * 8 + 4);
    f16x8 F;
#pragma unroll
    for (int j = 0; j < 4; ++j) { F[j] = (_Float16)v0[j]; F[4 + j] = (_Float16)v1[j]; }
    nf[kc] = F;
  }

  // ---- Phase 1: root = h @ Rt^T + conv_bias (8 MFMA)
  f32x4 racc[4];
#pragma unroll
  for (int t = 0; t < 4; ++t) racc[t] = conv_bias[t * 16 + col];
#pragma unroll
  for (int t = 0; t < 4; ++t)
#pragma unroll
    for (int kc = 0; kc < 2; ++kc)
      racc[t] = MFH(nf[kc], *(const f16x8*)(Rtp + t * 1024 + kc * 512 + lane * 8), racc[t]);

  // ---- Epilogue 1: m = lrelu(ag*invdeg + racc); aggr <- 0; m -> LDS (fp16, swizzled)
#pragma unroll
  for (int t = 0; t < 4; ++t) {
#pragma unroll
    for (int r = 0; r < 4; ++r) {
      int nn = nrow[r];
      if (nn < N_NODES_C) aggr[(size_t)nn * 64 + t * 16 + col] = 0.f;  // re-zero
      float mval = lrelu(ag[t][r] * invd[r] + racc[t][r]);
      int nl = kg * 4 + r;
      int dsw = (t * 16 + col) ^ ((nl & 7) << 3);
      ms[wv][nl * 64 + dsw] = (_Float16)mval;
    }
  }
  __syncthreads();

  f16x8 ma[2];
#pragma unroll
  for (int kc = 0; kc < 2; ++kc)
    ma[kc] = *(const f16x8*)&ms[wv][col * 64 + ((kc * 32 + kg * 8) ^ ((col & 7) << 3))];

  // ---- Phase 2: gi = m @ Wi^T + b_ih ; gh = h @ Wh^T + b_hh  (48 MFMA)
  f32x4 gi[12], gh[12];
#pragma unroll
  for (int t = 0; t < 12; ++t) { gi[t] = b_ih[t * 16 + col]; gh[t] = b_hh[t * 16 + col]; }
#pragma unroll
  for (int t = 0; t < 12; ++t)
#pragma unroll
    for (int kc = 0; kc < 2; ++kc) {
      gi[t] = MFH(ma[kc], *(const f16x8*)(Wip + t * 1024 + kc * 512 + lane * 8), gi[t]);
      gh[t] = MFH(nf[kc], *(const f16x8*)(Whp + t * 1024 + kc * 512 + lane * 8), gh[t]);
    }

  // ---- Epilogue 2: GRU combine, h -> nodeF
#pragma unroll
  for (int t = 0; t < 4; ++t) {
#pragma unroll
    for (int r = 0; r < 4; ++r) {
      int nn = nrow[r];
      if (nn >= N_NODES_C) continue;
      size_t idx = (size_t)nn * 64 + t * 16 + col;
      float hv = nodeF[idx];
      float rr = sigm(gi[t][r] + gh[t][r]);
      float zz = sigm(gi[t + 4][r] + gh[t + 4][r]);
      float nv = tanhf(gi[t + 8][r] + rr * gh[t + 8][r]);
      nodeF[idx] = (1.f - zz) * nv + zz * hv;
    }
  }
}

// ---------------------------------------------------------------- fused Set2Set (3 steps) + final linear
// 256 threads: LSTM gate-per-thread (192 FMA vs 768), attention 4 rows/iter.
__global__ __launch_bounds__(256) void set2set_kernel(
    const float* __restrict__ nodeF, const int* __restrict__ goff,
    const float* __restrict__ w_ih, const float* __restrict__ w_hh,
    const float* __restrict__ b_ih, const float* __restrict__ b_hh,
    const float* __restrict__ lw, const float* __restrict__ lb,
    float* __restrict__ ebuf, float* __restrict__ dout)
{
  const int g = blockIdx.x, tid = threadIdx.x;
  const int t = tid & 63, grp = tid >> 6;
  __shared__ float qs[128], hs[64], cls[64], gvs[4][64], red[4][64], scal[8];
  if (tid < 128) qs[tid] = 0.f;
  if (tid < 64) { hs[tid] = 0.f; cls[tid] = 0.f; }
  const int s0 = goff[g], s1 = goff[g + 1];
  __syncthreads();

  for (int step = 0; step < 3; ++step) {
    // ---- LSTM gates: thread (grp,t) computes gate grp, element t (192 FMA)
    {
      float s = b_ih[grp * 64 + t] + b_hh[grp * 64 + t];
      const float4* wi4 = (const float4*)(w_ih + (grp * 64 + t) * 128);
#pragma unroll 8
      for (int j = 0; j < 32; ++j) {
        float4 w = wi4[j];
        s += qs[4 * j] * w.x + qs[4 * j + 1] * w.y + qs[4 * j + 2] * w.z + qs[4 * j + 3] * w.w;
      }
      const float4* wh4 = (const float4*)(w_hh + (grp * 64 + t) * 64);
#pragma unroll 8
      for (int j = 0; j < 16; ++j) {
        float4 w = wh4[j];
        s += hs[4 * j] * w.x + hs[4 * j + 1] * w.y + hs[4 * j + 2] * w.z + hs[4 * j + 3] * w.w;
      }
      gvs[grp][t] = s;
    }
    __syncthreads();
    if (tid < 64) {
      float c = sigm(gvs[1][t]) * cls[t] + sigm(gvs[0][t]) * tanhf(gvs[2][t]);
      float hn = sigm(gvs[3][t]) * tanhf(c);
      cls[t] = c; hs[t] = hn; qs[t] = hn;
    }
    __syncthreads();
    const float qv = hs[t];

    // ---- attention pass 1: e_n + block emax (4 rows per iteration)
    float emax = -3.0e38f;
    for (int n = s0 + grp; n < s1; n += 4) {
      float p = nodeF[(size_t)n * 64 + t] * qv;
#pragma unroll
      for (int off = 32; off > 0; off >>= 1) p += __shfl_down(p, off);
      float en = __shfl(p, 0);
      if (t == 0) ebuf[n] = en;
      emax = fmaxf(emax, en);
    }
    if (t == 0) scal[grp] = emax;
    __syncthreads();  // also drains ebuf writes
    emax = fmaxf(fmaxf(scal[0], scal[1]), fmaxf(scal[2], scal[3]));

    // ---- pass 2: exp + block sum (stride 256)
    float lsum = 0.f;
    for (int n = s0 + tid; n < s1; n += 256) {
      float ex = __expf(ebuf[n] - emax);
      ebuf[n] = ex;
      lsum += ex;
    }
#pragma unroll
    for (int off = 32; off > 0; off >>= 1) lsum += __shfl_down(lsum, off);
    if (t == 0) scal[4 + grp] = lsum;
    __syncthreads();  // drains exp writes
    float denom = scal[4] + scal[5] + scal[6] + scal[7];

    // ---- pass 3: readout r[o] (4 rows per iteration, cross-group LDS reduce)
    float r = 0.f;
    for (int n = s0 + grp; n < s1; n += 4) r += ebuf[n] * nodeF[(size_t)n * 64 + t];
    red[grp][t] = r;
    __syncthreads();
    if (tid < 64) {
      float rr = red[0][t] + red[1][t] + red[2][t] + red[3][t];
      qs[64 + t] = (s1 > s0) ? rr / denom : 0.f;
    }
    __syncthreads();
  }
  // ---- final linear
  float sacc = (tid < 128) ? qs[tid] * lw[tid] : 0.f;
#pragma unroll
  for (int off = 32; off > 0; off >>= 1) sacc += __shfl_down(sacc, off);
  if (t == 0) scal[grp] = sacc;
  __syncthreads();
  if (tid == 0) dout[g] = scal[0] + scal[1] + lb[0];
}

// ---------------------------------------------------------------- launch
extern "C" void kernel_launch(void* const* d_in, const int* in_sizes, int n_in,
                              void* d_out, int out_size, void* d_ws, size_t ws_size,
                              hipStream_t stream) {
  const float* x         = (const float*)d_in[0];
  const int*   ei        = (const int*)  d_in[1];
  const float* eattr     = (const float*)d_in[2];
  const int*   batch     = (const int*)  d_in[3];
  const float* lin0_w    = (const float*)d_in[4];
  const float* lin0_b    = (const float*)d_in[5];
  const float* net_w1    = (const float*)d_in[6];
  const float* net_b1    = (const float*)d_in[7];
  const float* net_w2    = (const float*)d_in[8];
  const float* net_b2    = (const float*)d_in[9];
  const float* conv_root = (const float*)d_in[10];
  const float* conv_bias = (const float*)d_in[11];
  const float* gru_w_ih  = (const float*)d_in[12];
  const float* gru_w_hh  = (const float*)d_in[13];
  const float* gru_b_ih  = (const float*)d_in[14];
  const float* gru_b_hh  = (const float*)d_in[15];
  const float* lstm_w_ih = (const float*)d_in[16];
  const float* lstm_w_hh = (const float*)d_in[17];
  const float* lstm_b_ih = (const float*)d_in[18];
  const float* lstm_b_hh = (const float*)d_in[19];
  const float* lin_w     = (const float*)d_in[20];
  const float* lin_b     = (const float*)d_in[21];

  // workspace layout (~13.1 MB)
  float* ws    = (float*)d_ws;
  float* nodeF = ws;                         // 1,600,000 f
  float* aggr  = nodeF + 1600000;            // 1,600,000 f
  float* deg   = aggr + 1600000;             //    25,000 f
  float* ebuf  = deg + 25000;                //    25,000 f
  int*   goff  = (int*)(ebuf + 25000);       //     1,024 i
  _Float16* Rtp = (_Float16*)(goff + 1024);  //     4,096 h
  _Float16* Wip = Rtp + 4096;                //    12,288 h
  _Float16* Whp = Wip + 12288;               //    12,288 h
  _Float16* Wp  = Whp + 12288;               //   524,288 h
  _Float16* B2p = Wp + 524288;               //     4,096 h

  hipMemsetAsync(deg, 0, 25000 * sizeof(float), stream);
  hipMemsetAsync(aggr, 0, 1600000 * sizeof(float), stream);  // node_update re-zeroes thereafter

  lin0_kernel<<<(N_NODES_C + 3) / 4, 256, 0, stream>>>(x, lin0_w, lin0_b, nodeF);
  deg_kernel<<<(N_EDGES_C + 255) / 256, 256, 0, stream>>>(ei, batch, deg, goff);
  invdeg_kernel<<<(N_NODES_C + 255) / 256, 256, 0, stream>>>(deg);
  prep_kernel<<<2048, 256, 0, stream>>>(net_w2, net_b2, conv_root, gru_w_ih, gru_w_hh,
                                        Wp, B2p, Rtp, Wip, Whp);

  for (int step = 0; step < 3; ++step) {
    msg_kernel<<<(N_EDGES_C + EPB - 1) / EPB, 256, 0, stream>>>(
        nodeF, ei, eattr, net_w1, net_b1, Wp, B2p, aggr);
    node_update_kernel<<<(N_NODES_C + 31) / 32, 128, 0, stream>>>(
        aggr, deg, Rtp, Wip, Whp, conv_bias, gru_b_ih, gru_b_hh, nodeF);
  }

  set2set_kernel<<<N_GRAPHS_C, 256, 0, stream>>>(
      nodeF, goff, lstm_w_ih, lstm_w_hh, lstm_b_ih, lstm_b_hh, lin_w, lin_b, ebuf, (float*)d_out);
}